// Round 9
// baseline (1465.560 us; speedup 1.0000x reference)
//
#include <hip/hip_runtime.h>
#include <cfloat>
#include <math.h>

constexpr int B_ = 8, N_ = 4096, S_ = 1024, NS_ = 32;
constexpr int R_ = B_ * S_ * NS_;          // 262144 rows (b,s,k)
constexpr float EPS_ = 1e-5f;

typedef float v2f __attribute__((ext_vector_type(2)));

// ---------------------------------------------------------------- DPP helpers
__device__ __forceinline__ unsigned dpp_red_umax(unsigned x) {
    unsigned t;
#define STEP_(ctrl) t = (unsigned)__builtin_amdgcn_update_dpp((int)x, (int)x, ctrl, 0xf, 0xf, false); x = x > t ? x : t;
    STEP_(0x111) STEP_(0x112) STEP_(0x114) STEP_(0x118) STEP_(0x142) STEP_(0x143)
#undef STEP_
    return x;
}
__device__ __forceinline__ unsigned dpp_red_umin(unsigned x) {
    unsigned t;
#define STEP_(ctrl) t = (unsigned)__builtin_amdgcn_update_dpp((int)x, (int)x, ctrl, 0xf, 0xf, false); x = x < t ? x : t;
    STEP_(0x111) STEP_(0x112) STEP_(0x114) STEP_(0x118) STEP_(0x142) STEP_(0x143)
#undef STEP_
    return x;
}
__device__ __forceinline__ void dpp_min_u64(unsigned& hi, unsigned& lo) {
#define STEP_(ctrl) { \
    unsigned h2 = (unsigned)__builtin_amdgcn_update_dpp((int)hi, (int)hi, ctrl, 0xf, 0xf, false); \
    unsigned l2 = (unsigned)__builtin_amdgcn_update_dpp((int)lo, (int)lo, ctrl, 0xf, 0xf, false); \
    if (h2 < hi || (h2 == hi && l2 < lo)) { hi = h2; lo = l2; } }
    STEP_(0x111) STEP_(0x112) STEP_(0x114) STEP_(0x118) STEP_(0x142) STEP_(0x143)
#undef STEP_
}
__device__ __forceinline__ float dpp_sum_f32(float x) {
#define ADD_(ctrl, rm) { \
    int t_ = __builtin_amdgcn_update_dpp(0, __float_as_int(x), ctrl, rm, 0xf, true); \
    x += __int_as_float(t_); }
    ADD_(0x111, 0xf) ADD_(0x112, 0xf) ADD_(0x114, 0xf) ADD_(0x118, 0xf)
    ADD_(0x142, 0xa) ADD_(0x143, 0xc)
#undef ADD_
    return x;
}

// ---------------------------------------------------------------- FPS
// One block per batch, 512 threads x 8 strided points (4 x v2f). r8's exact
// per-point math (bit-identical); 2 waves/SIMD to hide DPP/LDS/barrier
// latency; two-phase 32-bit DPP reduce; 8-entry u64 LDS combine (parity
// double-buffer, single barrier per iter).
__global__ __launch_bounds__(512) void fps_kernel(const float* __restrict__ xyz,
                                                  int* __restrict__ ct_idx) {
    int b = blockIdx.x;
    const float* xb = xyz + (size_t)b * 3 * N_;
    int t = threadIdx.x;
    __shared__ float sx[N_], sy[N_], sz[N_];
    __shared__ unsigned long long sb[2][8];
    for (int i = t; i < N_; i += 512) {
        sx[i] = xb[i];
        sy[i] = xb[N_ + i];
        sz[i] = xb[2 * N_ + i];
    }
    v2f px[4], py[4], pz[4], dist[4];
#pragma unroll
    for (int k = 0; k < 4; k++) {
        int n0 = (2 * k) * 512 + t, n1 = (2 * k + 1) * 512 + t;
        px[k] = (v2f){xb[n0], xb[n1]};
        py[k] = (v2f){xb[N_ + n0], xb[N_ + n1]};
        pz[k] = (v2f){xb[2 * N_ + n0], xb[2 * N_ + n1]};
        dist[k] = (v2f){1e10f, 1e10f};
    }
    __syncthreads();
    float cx = sx[0], cy = sy[0], cz = sz[0];
    int far = 0;
    int w = t >> 6;
    for (int it = 0; it < S_; it++) {
        if (t == 0) ct_idx[b * S_ + it] = far;
        v2f cx2 = (v2f){cx, cx}, cy2 = (v2f){cy, cy}, cz2 = (v2f){cz, cz};
#pragma unroll
        for (int k = 0; k < 4; k++) {
            v2f dx = px[k] - cx2, dy = py[k] - cy2, dz = pz[k] - cz2;
            v2f d = dx * dx;
            d = __builtin_elementwise_fma(dy, dy, d);
            d = __builtin_elementwise_fma(dz, dz, d);   // bit-identical chain
            dist[k] = __builtin_elementwise_min(dist[k], d);
        }
        v2f m2a = __builtin_elementwise_max(dist[0], dist[1]);
        v2f m2b = __builtin_elementwise_max(dist[2], dist[3]);
        v2f m1 = __builtin_elementwise_max(m2a, m2b);
        float lmax = fmaxf(m1.x, m1.y);
        unsigned wm = (unsigned)__builtin_amdgcn_readlane(
            (int)dpp_red_umax(__float_as_uint(lmax)), 63);
        unsigned c4i[4];
#pragma unroll
        for (int k = 0; k < 4; k++) {
            unsigned a = (__float_as_uint(dist[k].x) == wm)
                             ? (unsigned)((2 * k) * 512 + t) : 0xffffffffu;
            unsigned bq = (__float_as_uint(dist[k].y) == wm)
                             ? (unsigned)((2 * k + 1) * 512 + t) : 0xffffffffu;
            c4i[k] = a < bq ? a : bq;
        }
        unsigned c01 = c4i[0] < c4i[1] ? c4i[0] : c4i[1];
        unsigned c23 = c4i[2] < c4i[3] ? c4i[2] : c4i[3];
        unsigned mn = dpp_red_umin(c01 < c23 ? c01 : c23);
        int p = it & 1;
        if ((t & 63) == 63)
            sb[p][w] = ((unsigned long long)wm << 32) | (unsigned)~mn;
        __syncthreads();
        unsigned long long b0 = sb[p][0], b1 = sb[p][1], b2 = sb[p][2], b3 = sb[p][3];
        unsigned long long b4 = sb[p][4], b5 = sb[p][5], b6 = sb[p][6], b7 = sb[p][7];
        unsigned long long ma = b0 > b1 ? b0 : b1;
        unsigned long long mb = b2 > b3 ? b2 : b3;
        unsigned long long mc = b4 > b5 ? b4 : b5;
        unsigned long long md = b6 > b7 ? b6 : b7;
        unsigned long long me = ma > mb ? ma : mb;
        unsigned long long mf = mc > md ? mc : md;
        unsigned long long bw = me > mf ? me : mf;
        far = (int)(~(unsigned)(bw & 0xffffffffu)) & (N_ - 1);
        cx = sx[far]; cy = sy[far]; cz = sz[far];
        // parity double-buffer: no trailing barrier needed
    }
}

// ---------------------------------------------------------------- kNN (+transpose fold)
// blocks < 8192: per-wave barrier-free top-32 over the wave's own 1024 pts
// (tree + DPP u64 min; marking via STATIC unrolled cndmask - no dynamic
// register indexing, so pk[] stays in VGPRs), then one barrier and a
// 128-candidate merge (exact, ascending (key,idx) = lax.top_k set & order).
// blocks >= 8192: pts/xyz transpose into point-major ptsT rows.
__global__ __launch_bounds__(256) void knn_kernel(const float* __restrict__ xyz,
                                                  const float* __restrict__ pts,
                                                  const int* __restrict__ ct_idx,
                                                  int* __restrict__ gidx,
                                                  float* __restrict__ ptsT) {
    if (blockIdx.x >= 8192) {
        int idx = (blockIdx.x - 8192) * 256 + threadIdx.x;   // 32768 points
        int b = idx >> 12, n = idx & (N_ - 1);
        float* row = ptsT + (size_t)idx * 32;
        const float* pb = pts + (size_t)b * 29 * N_;
#pragma unroll
        for (int c = 0; c < 29; c++) row[c] = pb[(size_t)c * N_ + n];
        const float* xb = xyz + (size_t)b * 3 * N_;
        row[29] = xb[n];
        row[30] = xb[N_ + n];
        row[31] = xb[2 * N_ + n];
        return;
    }
    int bs = blockIdx.x;
    int b = bs >> 10;
    const float* xb = xyz + (size_t)b * 3 * N_;
    int ci = ct_idx[bs];
    float cx = xb[ci], cy = xb[N_ + ci], cz = xb[2 * N_ + ci];
    float cs = cx * cx + cy * cy + cz * cz;
    int t = threadIdx.x;
    int w = t >> 6, lane = t & 63;
    unsigned long long pk[16];
#pragma unroll
    for (int j = 0; j < 16; j++) {
        int n = w * 1024 + j * 64 + lane;       // wave-contiguous ownership
        float x = xb[n], y = xb[N_ + n], z = xb[2 * N_ + n];
        float xn = x * x + y * y + z * z;
        float dot = cx * x + cy * y + cz * z;
        float val = cs + xn - 2.f * dot;        // reference formula order
        unsigned vb = __float_as_uint(val);
        unsigned key = (vb & 0x80000000u) ? ~vb : (vb | 0x80000000u);
        pk[j] = ((unsigned long long)key << 32) | (unsigned)n;
    }
    __shared__ unsigned long long cand[128];
    // phase 1: per-wave top-32, no block syncs
    for (int iter = 0; iter < NS_; iter++) {
        unsigned long long m8[8], m4[4];
#pragma unroll
        for (int j = 0; j < 8; j++) m8[j] = pk[2 * j] < pk[2 * j + 1] ? pk[2 * j] : pk[2 * j + 1];
#pragma unroll
        for (int j = 0; j < 4; j++) m4[j] = m8[2 * j] < m8[2 * j + 1] ? m8[2 * j] : m8[2 * j + 1];
        unsigned long long ma = m4[0] < m4[1] ? m4[0] : m4[1];
        unsigned long long mb = m4[2] < m4[3] ? m4[2] : m4[3];
        unsigned long long best = ma < mb ? ma : mb;
        unsigned hi = (unsigned)(best >> 32), lo = (unsigned)best;
        dpp_min_u64(hi, lo);
        unsigned whi = (unsigned)__builtin_amdgcn_readlane((int)hi, 63);
        unsigned wlo = (unsigned)__builtin_amdgcn_readlane((int)lo, 63);
        unsigned long long w64 = ((unsigned long long)whi << 32) | wlo;
        if (lane == 63) cand[w * NS_ + iter] = w64;
        // static-index marking: stays in VGPRs
#pragma unroll
        for (int j = 0; j < 16; j++)
            pk[j] = (pk[j] == w64) ? 0xFFFFFFFFFFFFFFFFull : pk[j];
    }
    __syncthreads();
    // phase 2: merge 4 sorted 32-lists (all waves redundantly; t==0 writes)
    unsigned long long c0 = cand[2 * lane], c1 = cand[2 * lane + 1];
    int out_base = bs * NS_;
    for (int iter = 0; iter < NS_; iter++) {
        unsigned long long mm = c0 < c1 ? c0 : c1;
        unsigned hi = (unsigned)(mm >> 32), lo = (unsigned)mm;
        dpp_min_u64(hi, lo);
        unsigned whi = (unsigned)__builtin_amdgcn_readlane((int)hi, 63);
        unsigned wlo = (unsigned)__builtin_amdgcn_readlane((int)lo, 63);
        unsigned long long w64 = ((unsigned long long)whi << 32) | wlo;
        if (t == 0) gidx[out_base + iter] = (int)wlo;
        c0 = (c0 == w64) ? 0xFFFFFFFFFFFFFFFFull : c0;
        c1 = (c1 == w64) ? 0xFFFFFFFFFFFFFFFFull : c1;
    }
}

// ---------------------------------------------------------------- gather (+ctp fused)
__global__ __launch_bounds__(256) void gather_kernel(const float* __restrict__ ptsT,
                                                     const float* __restrict__ xyz,
                                                     const int* __restrict__ ct_idx,
                                                     const int* __restrict__ gidx,
                                                     float* __restrict__ ft,
                                                     float* __restrict__ out) {
    int r = blockIdx.x * 256 + threadIdx.x;
    int b = r >> 15;
    int s = (r >> 5) & (S_ - 1);
    int g = gidx[r];
    int ci = ct_idx[b * S_ + s];
    const float4* rowg = (const float4*)(ptsT + ((size_t)(b << 12) + g) * 32);
    float4 v[8];
#pragma unroll
    for (int i = 0; i < 8; i++) v[i] = rowg[i];
    float4 cw = ((const float4*)(ptsT + ((size_t)(b << 12) + ci) * 32))[7]; // {c28,x,y,z}
    float rx = v[7].y - cw.y;
    float ry = v[7].z - cw.z;
    float rz = v[7].w - cw.w;
    ft[r] = rx;
    ft[(size_t)R_ + r] = ry;
    ft[(size_t)2 * R_ + r] = rz;
    float rd = sqrtf(fmaxf(rx * rx + ry * ry + rz * rz, 1e-12f));
    ft[(size_t)32 * R_ + r] = rd;
    const float vals[32] = {v[0].x, v[0].y, v[0].z, v[0].w, v[1].x, v[1].y, v[1].z, v[1].w,
                            v[2].x, v[2].y, v[2].z, v[2].w, v[3].x, v[3].y, v[3].z, v[3].w,
                            v[4].x, v[4].y, v[4].z, v[4].w, v[5].x, v[5].y, v[5].z, v[5].w,
                            v[6].x, v[6].y, v[6].z, v[6].w, v[7].x, 0.f, 0.f, 0.f};
#pragma unroll
    for (int c = 0; c < 29; c++) ft[(size_t)(3 + c) * R_ + r] = vals[c];
    if (r < B_ * 3 * S_) {
        int bb = r / (3 * S_);
        int rem = r - bb * 3 * S_;
        int cc = rem >> 10;
        int ss = rem & (S_ - 1);
        int cidx = ct_idx[bb * S_ + ss];
        out[r] = xyz[(size_t)bb * 3 * N_ + (size_t)cc * N_ + cidx];
    }
}

// ---------------------------------------------------------------- conv1x1
template <int CIN, bool PRO>
__global__ __launch_bounds__(256) void convk(const float* __restrict__ xin,
                                             const float* __restrict__ W,
                                             const float* __restrict__ bias,
                                             const float* __restrict__ pread,
                                             const float* __restrict__ g,
                                             const float* __restrict__ be,
                                             float* __restrict__ pwrite, int pofs,
                                             float* __restrict__ out0,
                                             float* __restrict__ out1) {
    __shared__ float Ws[CIN][64];
    __shared__ float bs_[64];
    __shared__ float as_[CIN], bbs[CIN];
    __shared__ float red[4][64][2];
    int oc0 = blockIdx.y * 64;
    for (int i = threadIdx.x; i < CIN * 64; i += 256) {
        int o = i & 63, c = i >> 6;
        Ws[c][o] = W[(size_t)(oc0 + o) * CIN + c];
    }
    if (threadIdx.x < 64) bs_[threadIdx.x] = bias[oc0 + threadIdx.x];
    if (PRO) {
        int c = threadIdx.x >> 2, sub = threadIdx.x & 3;
        const float* ps = pread + (size_t)c * 1024 + sub * 128;
        float s = 0.f, q = 0.f;
        for (int i = 0; i < 128; i++) { s += ps[i]; q += ps[512 + i]; }
        s += __shfl_xor(s, 1); s += __shfl_xor(s, 2);
        q += __shfl_xor(q, 1); q += __shfl_xor(q, 2);
        if (sub == 0) {
            float inv = 1.0f / (float)R_;
            float mean = s * inv;
            float var = q * inv - mean * mean;
            float a = g[c] / sqrtf(var + EPS_);
            as_[c] = a;
            bbs[c] = be[c] - mean * a;
        }
    }
    __syncthreads();
    size_t r0 = (size_t)blockIdx.x * 512 + threadIdx.x;
    float acc0[64], acc1[64];
#pragma unroll
    for (int o = 0; o < 64; o++) { acc0[o] = 0.f; acc1[o] = 0.f; }
    for (int c = 0; c < CIN; c++) {
        float x0 = xin[(size_t)c * R_ + r0];
        float x1 = xin[(size_t)c * R_ + r0 + 256];
        if (PRO) {
            float a = as_[c], bb = bbs[c];
            x0 = fmaxf(fmaf(a, x0, bb), 0.f);
            x1 = fmaxf(fmaf(a, x1, bb), 0.f);
        }
#pragma unroll
        for (int o = 0; o < 64; o++) {
            float w = Ws[c][o];
            acc0[o] = fmaf(x0, w, acc0[o]);
            acc1[o] = fmaf(x1, w, acc1[o]);
        }
    }
    float* outp = blockIdx.y ? out1 : out0;
    int wv = threadIdx.x >> 6;
#pragma unroll
    for (int o = 0; o < 64; o++) {
        float bv = bs_[o];
        float y0 = acc0[o] + bv;
        float y1 = acc1[o] + bv;
        outp[(size_t)o * R_ + r0] = y0;
        outp[(size_t)o * R_ + r0 + 256] = y1;
        float s = y0 + y1;
        float q = fmaf(y0, y0, y1 * y1);
        s = dpp_sum_f32(s);
        q = dpp_sum_f32(q);
        if ((threadIdx.x & 63) == 63) { red[wv][o][0] = s; red[wv][o][1] = q; }
    }
    __syncthreads();
    if (threadIdx.x < 64) {
        int o = threadIdx.x;
        float s = red[0][o][0] + red[1][o][0] + red[2][o][0] + red[3][o][0];
        float q = red[0][o][1] + red[1][o][1] + red[2][o][1] + red[3][o][1];
        pwrite[(size_t)(pofs + oc0 + o) * 1024 + blockIdx.x] = s;
        pwrite[(size_t)(pofs + oc0 + o) * 1024 + 512 + blockIdx.x] = q;
    }
}

// conv1 branch: 4 input channels = ft{0,1,2,32}
__global__ __launch_bounds__(256) void conv1_kernel(const float* __restrict__ ft,
                                                    const float* __restrict__ W,
                                                    const float* __restrict__ bias,
                                                    float* __restrict__ out,
                                                    float* __restrict__ pwrite, int pofs) {
    __shared__ float Ws[4][64];
    __shared__ float bs_[64];
    __shared__ float red[4][64][2];
    {
        int i = threadIdx.x;
        if (i < 256) { int o = i & 63, c = i >> 6; Ws[c][o] = W[o * 4 + c]; }
    }
    if (threadIdx.x < 64) bs_[threadIdx.x] = bias[threadIdx.x];
    __syncthreads();
    size_t r0 = (size_t)blockIdx.x * 512 + threadIdx.x;
    float acc0[64], acc1[64];
#pragma unroll
    for (int o = 0; o < 64; o++) { acc0[o] = 0.f; acc1[o] = 0.f; }
    const int chs[4] = {0, 1, 2, 32};
#pragma unroll
    for (int c = 0; c < 4; c++) {
        int ch = chs[c];
        float x0 = ft[(size_t)ch * R_ + r0];
        float x1 = ft[(size_t)ch * R_ + r0 + 256];
#pragma unroll
        for (int o = 0; o < 64; o++) {
            float w = Ws[c][o];
            acc0[o] = fmaf(x0, w, acc0[o]);
            acc1[o] = fmaf(x1, w, acc1[o]);
        }
    }
    int wv = threadIdx.x >> 6;
#pragma unroll
    for (int o = 0; o < 64; o++) {
        float bv = bs_[o];
        float y0 = acc0[o] + bv;
        float y1 = acc1[o] + bv;
        out[(size_t)o * R_ + r0] = y0;
        out[(size_t)o * R_ + r0 + 256] = y1;
        float s = y0 + y1;
        float q = fmaf(y0, y0, y1 * y1);
        s = dpp_sum_f32(s);
        q = dpp_sum_f32(q);
        if ((threadIdx.x & 63) == 63) { red[wv][o][0] = s; red[wv][o][1] = q; }
    }
    __syncthreads();
    if (threadIdx.x < 64) {
        int o = threadIdx.x;
        float s = red[0][o][0] + red[1][o][0] + red[2][o][0] + red[3][o][0];
        float q = red[0][o][1] + red[1][o][1] + red[2][o][1] + red[3][o][1];
        pwrite[(size_t)(pofs + o) * 1024 + blockIdx.x] = s;
        pwrite[(size_t)(pofs + o) * 1024 + 512 + blockIdx.x] = q;
    }
}

// ---------------------------------------------------------------- BN finalize
__global__ __launch_bounds__(64) void statsf(const float* __restrict__ partial,
                                             const float* __restrict__ g,
                                             const float* __restrict__ be,
                                             float* __restrict__ ab, int C) {
    int c = blockIdx.x, t = threadIdx.x;
    float s = 0.f, q = 0.f;
    for (int i = t; i < 512; i += 64) {
        s += partial[(size_t)c * 1024 + i];
        q += partial[(size_t)c * 1024 + 512 + i];
    }
    s = dpp_sum_f32(s);
    q = dpp_sum_f32(q);
    if (t == 63) {
        float inv = 1.0f / (float)R_;
        float mean = s * inv;
        float var = q * inv - mean * mean;
        float a = g[c] / sqrtf(var + EPS_);
        ab[c] = a;
        ab[C + c] = be[c] - mean * a;
    }
}

__global__ __launch_bounds__(64) void statsf2(const float* __restrict__ partial,
                                              const float* __restrict__ g1,
                                              const float* __restrict__ be1,
                                              const float* __restrict__ g2,
                                              const float* __restrict__ be2,
                                              float* __restrict__ ab) {
    int c = blockIdx.x, t = threadIdx.x;
    float s = 0.f, q = 0.f;
    for (int i = t; i < 512; i += 64) {
        s += partial[(size_t)c * 1024 + i];
        q += partial[(size_t)c * 1024 + 512 + i];
    }
    s = dpp_sum_f32(s);
    q = dpp_sum_f32(q);
    if (t == 63) {
        float gv = c < 64 ? g1[c] : g2[c - 64];
        float bv = c < 64 ? be1[c] : be2[c - 64];
        float inv = 1.0f / (float)R_;
        float mean = s * inv;
        float var = q * inv - mean * mean;
        float a = gv / sqrtf(var + EPS_);
        ab[c] = a;
        ab[128 + c] = bv - mean * a;
    }
}

// ---------------------------------------------------------------- epilogues
__global__ __launch_bounds__(128) void final_max(const float* __restrict__ yA,
                                                 const float* __restrict__ yC,
                                                 const float* __restrict__ ab,
                                                 float* __restrict__ out) {
    int bs = blockIdx.x;
    int c = threadIdx.x;
    const float* src = (c < 64 ? yA + (size_t)c * R_ : yC + (size_t)(c - 64) * R_) + (size_t)bs * NS_;
    float a = ab[c], bb = ab[128 + c];
    const float4* s4 = reinterpret_cast<const float4*>(src);
    float m = -FLT_MAX;
#pragma unroll
    for (int i = 0; i < 8; i++) {
        float4 v = s4[i];
        m = fmaxf(m, fmaxf(fmaf(a, v.x, bb), 0.f));
        m = fmaxf(m, fmaxf(fmaf(a, v.y, bb), 0.f));
        m = fmaxf(m, fmaxf(fmaf(a, v.z, bb), 0.f));
        m = fmaxf(m, fmaxf(fmaf(a, v.w, bb), 0.f));
    }
    int b = bs >> 10, s = bs & (S_ - 1);
    out[24576 + (size_t)b * 393216 + (size_t)c * 1024 + s] = m;
}

__global__ __launch_bounds__(128) void final_meanmax(const float* __restrict__ z1,
                                                     const float* __restrict__ z2,
                                                     const float* __restrict__ ab,
                                                     float* __restrict__ out) {
    int bs = blockIdx.x;
    int c = threadIdx.x;
    const float* src = (c < 64 ? z1 + (size_t)c * R_ : z2 + (size_t)(c - 64) * R_) + (size_t)bs * NS_;
    float a = ab[c], bb = ab[128 + c];
    const float4* s4 = reinterpret_cast<const float4*>(src);
    float m = -FLT_MAX, sm = 0.f;
#pragma unroll
    for (int i = 0; i < 8; i++) {
        float4 v = s4[i];
        float t0 = fmaxf(fmaf(a, v.x, bb), 0.f); sm += t0; m = fmaxf(m, t0);
        float t1 = fmaxf(fmaf(a, v.y, bb), 0.f); sm += t1; m = fmaxf(m, t1);
        float t2 = fmaxf(fmaf(a, v.z, bb), 0.f); sm += t2; m = fmaxf(m, t2);
        float t3 = fmaxf(fmaf(a, v.w, bb), 0.f); sm += t3; m = fmaxf(m, t3);
    }
    int b = bs >> 10, s = bs & (S_ - 1);
    size_t ob = 24576 + (size_t)b * 393216;
    out[ob + (size_t)(128 + c) * 1024 + s] = sm * 0.03125f;
    out[ob + (size_t)(256 + c) * 1024 + s] = m;
}

// ================================================================ launch
extern "C" void kernel_launch(void* const* d_in, const int* in_sizes, int n_in,
                              void* d_out, int out_size, void* d_ws, size_t ws_size,
                              hipStream_t stream) {
    const float* xyz = (const float*)d_in[0];
    const float* pts = (const float*)d_in[1];
    const float* W0 = (const float*)d_in[2];  const float* b0 = (const float*)d_in[3];
    const float* g0 = (const float*)d_in[4];  const float* be0 = (const float*)d_in[5];
    const float* W1 = (const float*)d_in[6];  const float* b1 = (const float*)d_in[7];
    const float* g1 = (const float*)d_in[8];  const float* be1 = (const float*)d_in[9];
    const float* W2 = (const float*)d_in[10]; const float* b2 = (const float*)d_in[11];
    const float* g2 = (const float*)d_in[12]; const float* be2 = (const float*)d_in[13];
    const float* c1w = (const float*)d_in[14]; const float* c1b = (const float*)d_in[15];
    const float* bg1 = (const float*)d_in[16]; const float* bbe1 = (const float*)d_in[17];
    const float* c2w = (const float*)d_in[18]; const float* c2b = (const float*)d_in[19];
    const float* bg2 = (const float*)d_in[20]; const float* bbe2 = (const float*)d_in[21];
    float* out = (float*)d_out;

    // workspace layout
    int* ct_idx = (int*)d_ws;                       // [8192]
    int* gidx = ct_idx + B_ * S_;                   // [262144]
    float* fbase = (float*)d_ws;
    float* ft = fbase + 270336;                     // 33*R
    float* A = ft + (size_t)33 * R_;                // 64*R  (ptsT alias -> y0 -> y2.lo -> z1)
    float* Bb = A + (size_t)64 * R_;                // 64*R  (y1 -> z2)
    float* C = Bb + (size_t)64 * R_;                // 64*R  (y2.hi)
    float* pbufA = C + (size_t)64 * R_;             // 128*1024
    float* pbufB = pbufA + 131072;                  // 128*1024
    float* ab2 = pbufB + 131072;                    // 256
    float* abz = ab2 + 256;                         // 256
    float* ptsT = A;                                // consumed before conv0 writes A

    fps_kernel<<<B_, 512, 0, stream>>>(xyz, ct_idx);
    knn_kernel<<<B_ * S_ + 128, 256, 0, stream>>>(xyz, pts, ct_idx, gidx, ptsT);
    gather_kernel<<<R_ / 256, 256, 0, stream>>>(ptsT, xyz, ct_idx, gidx, ft, out);

    // MLP stack (ab0/ab1 fused into consumer prologues; partials double-buffered)
    convk<32, false><<<dim3(R_ / 512, 1), 256, 0, stream>>>(ft, W0, b0, nullptr, nullptr, nullptr, pbufA, 0, A, nullptr);
    convk<64, true><<<dim3(R_ / 512, 1), 256, 0, stream>>>(A, W1, b1, pbufA, g0, be0, pbufB, 0, Bb, nullptr);
    convk<64, true><<<dim3(R_ / 512, 2), 256, 0, stream>>>(Bb, W2, b2, pbufB, g1, be1, pbufA, 0, A, C);
    statsf<<<128, 64, 0, stream>>>(pbufA, g2, be2, ab2, 128);
    final_max<<<B_ * S_, 128, 0, stream>>>(A, C, ab2, out);

    // branch convs (ft -> z2 in Bb, z1 in A), combined stats, final
    convk<32, false><<<dim3(R_ / 512, 1), 256, 0, stream>>>(ft, c2w, c2b, nullptr, nullptr, nullptr, pbufB, 64, Bb, nullptr);
    conv1_kernel<<<R_ / 512, 256, 0, stream>>>(ft, c1w, c1b, A, pbufB, 0);
    statsf2<<<128, 64, 0, stream>>>(pbufB, bg1, bbe1, bg2, bbe2, abz);
    final_meanmax<<<B_ * S_, 128, 0, stream>>>(A, Bb, abz, out);
}